// Round 1
// baseline (3003.630 us; speedup 1.0000x reference)
//
#include <hip/hip_runtime.h>
#include <hip/hip_bf16.h>

// Problem constants (match reference)
#define Bsz 8
#define Ssz 2048
#define PLM 768
#define Gd  256
#define N_WM 50000
#define E_WM 800000
#define N_F  16384   // B*S
#define E_F  131072
#define Kc   4

// ---------------------------------------------------------------------------
// scatter-add: m[dst[e]] += h[src[e]], one block per edge, 256 feats/thread
// ---------------------------------------------------------------------------
__global__ void scatter_add_kernel(const float* __restrict__ h,
                                   const int* __restrict__ src,
                                   const int* __restrict__ dst,
                                   float* __restrict__ m, int E) {
    int e = blockIdx.x;
    if (e >= E) return;
    int f = threadIdx.x;
    int s = src[e], d = dst[e];
    atomicAdd(&m[(size_t)d * Gd + f], h[(size_t)s * Gd + f]);
}

// ---------------------------------------------------------------------------
// tmp[i] = sum_k table[token2nodepos[i,k]+2]  (table = [extra_emb; gemb])
// ---------------------------------------------------------------------------
__global__ void tmp_kernel(const float* __restrict__ gemb,
                           const float* __restrict__ extra,
                           const int* __restrict__ t2np,
                           float* __restrict__ D) {
    int i = blockIdx.x;
    int f = threadIdx.x;
    float s = 0.f;
#pragma unroll
    for (int k = 0; k < Kc; ++k) {
        int idx = t2np[i * Kc + k] + 2;
        const float* row = (idx < 2) ? (extra + (size_t)idx * Gd)
                                     : (gemb + (size_t)(idx - 2) * Gd);
        s += row[f];
    }
    D[(size_t)i * Gd + f] = s;
}

// ---------------------------------------------------------------------------
// row gather: F[i] = E[ids[i]]
// ---------------------------------------------------------------------------
__global__ void gather_kernel(const float* __restrict__ Ein,
                              const int* __restrict__ ids,
                              float* __restrict__ F) {
    int i = blockIdx.x;
    int f = threadIdx.x;
    F[(size_t)i * Gd + f] = Ein[(size_t)ids[i] * Gd + f];
}

// ---------------------------------------------------------------------------
// Tiled fp32 GEMM: C = act(Aeff @ W + b)
// MODE 0: A = p0[row*K + k]                                     (plain)
// MODE 1: A = p0[row*256+k] + p1[row*256+k]                     (h + m), K=256
// MODE 2: A = k<256 ? p0[row*256+k] : p1[row*768 + k-256]       (tmp|text), K=1024
// MODE 3: A = k<768 ? p0 : (k<1024 ? p1 : p2)                   (text|tmp|temporal), K=1280
// ---------------------------------------------------------------------------
#define BM 64
#define BN 64
#define BK 16

template <int MODE>
__global__ __launch_bounds__(256) void gemm_kernel(
    const float* __restrict__ p0, const float* __restrict__ p1,
    const float* __restrict__ p2, const float* __restrict__ W,
    const float* __restrict__ bias, float* __restrict__ C,
    int M, int N, int K, int relu) {
    __shared__ float As[BM][BK + 1];
    __shared__ float Bs[BK][BN];

    int tid = threadIdx.x;
    int row0 = blockIdx.y * BM;
    int col0 = blockIdx.x * BN;
    int tx = tid & 15, ty = tid >> 4;

    float acc[4][4] = {};

    for (int k0 = 0; k0 < K; k0 += BK) {
        // stage A tile (64x16), 4 elems/thread
#pragma unroll
        for (int l = tid; l < BM * BK; l += 256) {
            int r = l / BK, kk = l % BK;
            int grow = row0 + r, gk = k0 + kk;
            float v = 0.f;
            if (grow < M) {
                if (MODE == 0) {
                    v = p0[(size_t)grow * K + gk];
                } else if (MODE == 1) {
                    v = p0[(size_t)grow * 256 + gk] + p1[(size_t)grow * 256 + gk];
                } else if (MODE == 2) {
                    v = (gk < 256) ? p0[(size_t)grow * 256 + gk]
                                   : p1[(size_t)grow * 768 + (gk - 256)];
                } else {
                    if (gk < 768)       v = p0[(size_t)grow * 768 + gk];
                    else if (gk < 1024) v = p1[(size_t)grow * 256 + (gk - 768)];
                    else                v = p2[(size_t)grow * 256 + (gk - 1024)];
                }
            }
            As[r][kk] = v;
        }
        // stage W tile (16x64), coalesced on N
#pragma unroll
        for (int l = tid; l < BK * BN; l += 256) {
            int kr = l / BN, c = l % BN;
            Bs[kr][c] = W[(size_t)(k0 + kr) * N + col0 + c];
        }
        __syncthreads();

#pragma unroll
        for (int kk = 0; kk < BK; ++kk) {
            float a[4], b[4];
#pragma unroll
            for (int i = 0; i < 4; ++i) a[i] = As[ty * 4 + i][kk];
#pragma unroll
            for (int j = 0; j < 4; ++j) b[j] = Bs[kk][tx * 4 + j];
#pragma unroll
            for (int i = 0; i < 4; ++i)
#pragma unroll
                for (int j = 0; j < 4; ++j) acc[i][j] += a[i] * b[j];
        }
        __syncthreads();
    }

#pragma unroll
    for (int i = 0; i < 4; ++i) {
        int r = row0 + ty * 4 + i;
        if (r >= M) continue;
#pragma unroll
        for (int j = 0; j < 4; ++j) {
            int c = col0 + tx * 4 + j;
            float v = acc[i][j] + bias[c];
            if (relu) v = fmaxf(v, 0.f);
            C[(size_t)r * N + c] = v;
        }
    }
}

// ---------------------------------------------------------------------------
extern "C" void kernel_launch(void* const* d_in, const int* in_sizes, int n_in,
                              void* d_out, int out_size, void* d_ws, size_t ws_size,
                              hipStream_t stream) {
    const float* text    = (const float*)d_in[0];   // [16384, 768]
    const float* wm_x    = (const float*)d_in[1];   // [50000, 256]
    const int*   wm_ei   = (const int*)d_in[2];     // [2, 800000]
    const int*   t2np    = (const int*)d_in[3];     // [16384, 4]
    const int*   f_ids   = (const int*)d_in[4];     // [16384]
    const int*   f_ei    = (const int*)d_in[5];     // [2, 131072]
    const float* extra   = (const float*)d_in[6];   // [2, 256]
    const float* wm_W1   = (const float*)d_in[7];
    const float* wm_b1   = (const float*)d_in[8];
    const float* wm_W2   = (const float*)d_in[9];
    const float* wm_b2   = (const float*)d_in[10];
    const float* fs_W1   = (const float*)d_in[11];
    const float* fs_b1   = (const float*)d_in[12];
    const float* fs_W2   = (const float*)d_in[13];
    const float* fs_b2   = (const float*)d_in[14];
    const float* fc1_W   = (const float*)d_in[15];  // [1024, 256]
    const float* fc1_b   = (const float*)d_in[16];
    const float* fc3_W   = (const float*)d_in[17];  // [1280, 768]
    const float* fc3_b   = (const float*)d_in[18];
    float* out = (float*)d_out;                     // [16384, 768]

    // workspace layout (fp32)
    float* A  = (float*)d_ws;                 // [50000,256] m-buffer (reused as fstm m)
    float* Bb = A  + (size_t)N_WM * Gd;       // [50000,256] wm h1 (reused: F, H)
    float* Cc = Bb + (size_t)N_WM * Gd;       // [50000,256] gemb (reused: E, T)
    float* D  = Cc + (size_t)N_WM * Gd;       // [16384,256] tmp

    float* F  = Bb;                           // [16384,256] gathered x
    float* H  = Bb + (size_t)N_F * Gd;        // [16384,256] fstm h1
    float* Ee = Cc;                           // [16384,256] graph_text_embed
    float* T  = Cc + (size_t)N_F * Gd;        // [16384,256] temporal

    const int* wm_src = wm_ei;
    const int* wm_dst = wm_ei + E_WM;
    const int* f_src  = f_ei;
    const int* f_dst  = f_ei + E_F;

    const size_t wm_m_bytes = (size_t)N_WM * Gd * sizeof(float);
    const size_t fs_m_bytes = (size_t)N_F * Gd * sizeof(float);

    dim3 blk(256);

    // ===== WM layer 1 =====
    hipMemsetAsync(A, 0, wm_m_bytes, stream);
    scatter_add_kernel<<<E_WM, blk, 0, stream>>>(wm_x, wm_src, wm_dst, A, E_WM);
    {
        dim3 grid(Gd / BN, (N_WM + BM - 1) / BM);
        gemm_kernel<1><<<grid, blk, 0, stream>>>(wm_x, A, nullptr, wm_W1, wm_b1,
                                                 Bb, N_WM, Gd, Gd, 1);
    }
    // ===== WM layer 2 =====
    hipMemsetAsync(A, 0, wm_m_bytes, stream);
    scatter_add_kernel<<<E_WM, blk, 0, stream>>>(Bb, wm_src, wm_dst, A, E_WM);
    {
        dim3 grid(Gd / BN, (N_WM + BM - 1) / BM);
        gemm_kernel<1><<<grid, blk, 0, stream>>>(Bb, A, nullptr, wm_W2, wm_b2,
                                                 Cc, N_WM, Gd, Gd, 1);
    }
    // ===== tmp (K-slot gather-sum) =====
    tmp_kernel<<<N_F, blk, 0, stream>>>(Cc, extra, t2np, D);
    // ===== fc1: E = concat(tmp, text) @ fc1_W + b =====
    {
        dim3 grid(Gd / BN, N_F / BM);
        gemm_kernel<2><<<grid, blk, 0, stream>>>(D, text, nullptr, fc1_W, fc1_b,
                                                 Ee, N_F, Gd, Gd + PLM, 0);
    }
    // ===== FSTM gather =====
    gather_kernel<<<N_F, blk, 0, stream>>>(Ee, f_ids, F);
    // ===== FSTM layer 1 =====
    hipMemsetAsync(A, 0, fs_m_bytes, stream);
    scatter_add_kernel<<<E_F, blk, 0, stream>>>(F, f_src, f_dst, A, E_F);
    {
        dim3 grid(Gd / BN, N_F / BM);
        gemm_kernel<1><<<grid, blk, 0, stream>>>(F, A, nullptr, fs_W1, fs_b1,
                                                 H, N_F, Gd, Gd, 1);
    }
    // ===== FSTM layer 2 =====
    hipMemsetAsync(A, 0, fs_m_bytes, stream);
    scatter_add_kernel<<<E_F, blk, 0, stream>>>(H, f_src, f_dst, A, E_F);
    {
        dim3 grid(Gd / BN, N_F / BM);
        gemm_kernel<1><<<grid, blk, 0, stream>>>(H, A, nullptr, fs_W2, fs_b2,
                                                 T, N_F, Gd, Gd, 1);
    }
    // ===== fc3: out = concat(text, tmp, temporal) @ fc3_W + b =====
    {
        dim3 grid(PLM / BN, N_F / BM);
        gemm_kernel<3><<<grid, blk, 0, stream>>>(text, D, T, fc3_W, fc3_b,
                                                 out, N_F, PLM, PLM + 2 * Gd, 0);
    }
}